// Round 6
// baseline (326.675 us; speedup 1.0000x reference)
//
#include <hip/hip_runtime.h>
#include <math.h>
#include <stdint.h>

#define HW_N 2304
#define CB   384
#define HIDD 512
#define HID2 1024      // fused w1||s1
#define DD   128
#define KK   64
#define BATCH 32
#define M1   65
#define NTOK (BATCH * HW_N)   // 73728 flattened tokens
#define NORM_ARG 2368.0f

typedef __bf16 bf16;
typedef __bf16 bf16x8 __attribute__((ext_vector_type(8)));
typedef float  f32x4  __attribute__((ext_vector_type(4)));

__device__ __forceinline__ void gld16(void* lds, const void* g) {
    __builtin_amdgcn_global_load_lds(
        (const __attribute__((address_space(1))) uint32_t*)g,
        (__attribute__((address_space(3))) uint32_t*)lds, 16, 0, 0);
}

template<int N> __device__ __forceinline__ void waitvm() {
    if constexpr (N == 0) asm volatile("s_waitcnt vmcnt(0)" ::: "memory");
    else if constexpr (N == 3) asm volatile("s_waitcnt vmcnt(3)" ::: "memory");
    else if constexpr (N == 4) asm volatile("s_waitcnt vmcnt(4)" ::: "memory");
    else if constexpr (N == 8) asm volatile("s_waitcnt vmcnt(8)" ::: "memory");
}

// ---------------------------------------------------------------------------
// x[b][CB][HW_N] f32 -> xT[b][HW_N][CB] bf16, all batches
// ---------------------------------------------------------------------------
__global__ __launch_bounds__(256)
void x_to_bf16T(const float* __restrict__ x, bf16* __restrict__ xT)
{
    const int b  = blockIdx.z;
    const int n0 = blockIdx.x * 64;
    const int c0 = blockIdx.y * 64;
    __shared__ float t[64][65];
    const int tx = threadIdx.x & 15, ty = threadIdx.x >> 4;
    const float* xb = x + (long)b * CB * HW_N;
    #pragma unroll
    for (int r = 0; r < 64; r += 16) {
        const float4 vv = *(const float4*)&xb[(long)(c0 + r + ty) * HW_N + n0 + tx * 4];
        t[r + ty][tx * 4 + 0] = vv.x; t[r + ty][tx * 4 + 1] = vv.y;
        t[r + ty][tx * 4 + 2] = vv.z; t[r + ty][tx * 4 + 3] = vv.w;
    }
    __syncthreads();
    bf16* ob = xT + (long)b * HW_N * CB;
    #pragma unroll
    for (int r = 0; r < 64; r += 16) {
        const int n = r + ty;
        union { bf16 h[4]; uint2 u2; } pk;
        pk.h[0] = (bf16)t[tx * 4 + 0][n]; pk.h[1] = (bf16)t[tx * 4 + 1][n];
        pk.h[2] = (bf16)t[tx * 4 + 2][n]; pk.h[3] = (bf16)t[tx * 4 + 3][n];
        *(uint2*)&ob[(long)(n0 + n) * CB + c0 + tx * 4] = pk.u2;
    }
}

__global__ __launch_bounds__(256)
void f2bf4(const float* __restrict__ in, bf16* __restrict__ out, int n4)
{
    int i = blockIdx.x * 256 + threadIdx.x;
    if (i < n4) {
        float4 vv = ((const float4*)in)[i];
        union { bf16 h[4]; uint2 u2; } pk;
        pk.h[0] = (bf16)vv.x; pk.h[1] = (bf16)vv.y;
        pk.h[2] = (bf16)vv.z; pk.h[3] = (bf16)vv.w;
        ((uint2*)out)[i] = pk.u2;
    }
}

__global__ __launch_bounds__(256)
void concat_bias(const float* __restrict__ b1, const float* __restrict__ c1,
                 float* __restrict__ bc)
{
    int i = blockIdx.x * 256 + threadIdx.x;
    if (i < HIDD) bc[i] = b1[i];
    else if (i < HID2) bc[i] = c1[i - HIDD];
}

// ---------------------------------------------------------------------------
// 8-wave counted-vmcnt MFMA GEMM (512 threads, waves 2x4).
//   OUT(ra, rb) = act( A[ra][:K] . B[rb][:K] + bias )
// Tile BA = 2*FA*16 A-rows x BB = 4*FB*16 B-rows, K-tile = BK.
// Pipeline: depth-2 LDS double-buffer; stage(t+2) issued after the
// read-release barrier; end-of-iter waits vmcnt(GAB) (counted, NEVER 0
// mid-loop) so the freshly-issued loads stay in flight across the barrier.
// BK==64 rows (128 B) are a 16-way bank-class collision on ds_read_b128:
// fixed by XOR-ing byte bits 4-6 with (row&7) on BOTH the pre-swizzled
// global source (gld16 writes linearly) and the ds_read address.
// BK==32 rows (64 B) are already uniform across bank-quads: no swizzle
// (measured r3/r4: swizzle at BK=32 changed nothing).
// OUT_MODE 0: OUT[rb][ra] bf16 (bias on ra, packed along ra)
// OUT_MODE 1: ra = token -> (b, n); OUT[((b*ldo)+rb)*HW_N + n] bf16
// OUT_MODE 2: same addressing, f32 (bias on rb for modes 1/2)
// ---------------------------------------------------------------------------
template<int FA, int FB, int BK, int OUT_MODE, bool RELU, int MINW>
__global__ __launch_bounds__(512, MINW)
void mfma_gemm8(const bf16* __restrict__ A, int lda,
                const bf16* __restrict__ B, int ldb,
                const float* __restrict__ bias,
                void* __restrict__ OUT, int ldo,
                int K, int nA)
{
    constexpr int BA = 2 * FA * 16;
    constexpr int BB = 4 * FB * 16;
    constexpr int KS = BK / 32;          // 32-wide MFMA sub-steps per K-tile
    constexpr int ROWB = BK * 2;         // bytes per LDS row
    constexpr int RPC  = 1024 / ROWB;    // rows per 1KiB wave-chunk
    constexpr int LPR  = ROWB / 16;      // lanes per row while staging
    constexpr int GA = (BA * ROWB) / 8192;   // gld16 per wave for A tile
    constexpr int GB = (BB * ROWB) / 8192;
    constexpr int GAB = GA + GB;

    __shared__ __align__(16) bf16 As[2][BA * BK];
    __shared__ __align__(16) bf16 Bs[2][BB * BK];

    int L = blockIdx.x;
    { const int cpx = gridDim.x >> 3; L = (L & 7) * cpx + (L >> 3); }
    const int ta = L % nA;
    const int tb = L / nA;

    const int tid  = threadIdx.x;
    const int lane = tid & 63;
    const int w    = tid >> 6;           // 0..7
    const int wr   = w >> 2;             // 0..1  (A-side)
    const int wc   = w & 3;              // 0..3  (B-side)

    const char* Ap = (const char*)A + (long)ta * BA * lda * 2;
    const char* Bp = (const char*)B + (long)tb * BB * ldb * 2;
    const long ldab = (long)lda * 2, ldbb = (long)ldb * 2;

    // staging lane constants (global source pre-swizzled for BK=64)
    const int subrow = lane / LPR;
    const int cslot  = lane % LPR;
    const int colb   = (BK == 64) ? ((cslot ^ (subrow & 7)) << 4) : (cslot << 4);

    // frag-read lane constants
    const int rl = lane & 15, q = lane >> 4;
    int koff[KS];
    #pragma unroll
    for (int ks = 0; ks < KS; ++ks)
        koff[ks] = (BK == 64) ? ((((ks << 2) | q) ^ (rl & 7)) << 4) : (q << 4);

    f32x4 acc[FA][FB];
    #pragma unroll
    for (int i = 0; i < FA; i++)
        #pragma unroll
        for (int j = 0; j < FB; j++)
            acc[i][j] = (f32x4){0.f, 0.f, 0.f, 0.f};

    const int nsteps = K / BK;

    auto stageA = [&](int buf, int kt) {
        #pragma unroll
        for (int g = 0; g < GA; ++g) {
            const int row = (g * 8 + w) * RPC + subrow;
            gld16((char*)As[buf] + (g * 8 + w) * 1024,
                  Ap + (long)row * ldab + (long)kt * ROWB + colb);
        }
    };
    auto stageB = [&](int buf, int kt) {
        #pragma unroll
        for (int g = 0; g < GB; ++g) {
            const int row = (g * 8 + w) * RPC + subrow;
            gld16((char*)Bs[buf] + (g * 8 + w) * 1024,
                  Bp + (long)row * ldbb + (long)kt * ROWB + colb);
        }
    };

    // prologue: two tiles in flight
    stageA(0, 0); stageB(0, 0);
    stageA(1, 1); stageB(1, 1);
    waitvm<GAB>();                       // tile 0 landed; tile 1 in flight
    __builtin_amdgcn_s_barrier();

    for (int t = 0; t < nsteps; ++t) {
        const int cur = t & 1;
        const char* Ab = (const char*)As[cur];
        const char* Bb = (const char*)Bs[cur];

        #pragma unroll
        for (int ks = 0; ks < KS; ++ks) {
            bf16x8 a[FA], bb[FB];
            #pragma unroll
            for (int i = 0; i < FA; i++) {
                const int row = wr * FA * 16 + i * 16 + rl;
                a[i] = *(const bf16x8*)(Ab + row * ROWB + koff[ks]);
            }
            #pragma unroll
            for (int j = 0; j < FB; j++) {
                const int row = wc * FB * 16 + j * 16 + rl;
                bb[j] = *(const bf16x8*)(Bb + row * ROWB + koff[ks]);
            }
            __builtin_amdgcn_s_setprio(1);
            #pragma unroll
            for (int i = 0; i < FA; i++)
                #pragma unroll
                for (int j = 0; j < FB; j++)
                    acc[i][j] = __builtin_amdgcn_mfma_f32_16x16x32_bf16(a[i], bb[j], acc[i][j], 0, 0, 0);
            __builtin_amdgcn_s_setprio(0);
        }

        asm volatile("s_waitcnt lgkmcnt(0)" ::: "memory");  // my reads of buf[cur] done
        __builtin_amdgcn_s_barrier();                       // everyone's reads done
        if (t + 2 < nsteps) { stageA(cur, t + 2); stageB(cur, t + 2); }
        if (t + 1 < nsteps) {
            if (t + 2 < nsteps) waitvm<GAB>(); else waitvm<0>();
            __builtin_amdgcn_s_barrier();                   // buf[nxt] ready
        }
    }

    const int fr = lane & 15;
    const int fq = lane >> 4;

    if (OUT_MODE == 0) {
        #pragma unroll
        for (int i = 0; i < FA; i++) {
            const int ra0 = ta * BA + wr * FA * 16 + i * 16 + fq * 4;
            const float4 bv = *(const float4*)&bias[ra0];
            #pragma unroll
            for (int j = 0; j < FB; j++) {
                const int rb = tb * BB + wc * FB * 16 + j * 16 + fr;
                union { bf16 h[4]; uint2 u2; } pk;
                float v0 = acc[i][j][0] + bv.x, v1 = acc[i][j][1] + bv.y;
                float v2 = acc[i][j][2] + bv.z, v3 = acc[i][j][3] + bv.w;
                if (RELU) {
                    v0 = fmaxf(v0, 0.f); v1 = fmaxf(v1, 0.f);
                    v2 = fmaxf(v2, 0.f); v3 = fmaxf(v3, 0.f);
                }
                pk.h[0] = (bf16)v0; pk.h[1] = (bf16)v1;
                pk.h[2] = (bf16)v2; pk.h[3] = (bf16)v3;
                *(uint2*)&((bf16*)OUT)[(long)rb * ldo + ra0] = pk.u2;
            }
        }
    } else {
        #pragma unroll
        for (int i = 0; i < FA; i++) {
            const int g0 = ta * BA + wr * FA * 16 + i * 16 + fq * 4;
            const int bi = g0 / HW_N;
            const int nn = g0 - bi * HW_N;
            #pragma unroll
            for (int j = 0; j < FB; j++) {
                const int mg = tb * BB + wc * FB * 16 + j * 16 + fr;
                const float bvs = bias[mg];
                float v0 = acc[i][j][0] + bvs, v1 = acc[i][j][1] + bvs;
                float v2 = acc[i][j][2] + bvs, v3 = acc[i][j][3] + bvs;
                if (RELU) {
                    v0 = fmaxf(v0, 0.f); v1 = fmaxf(v1, 0.f);
                    v2 = fmaxf(v2, 0.f); v3 = fmaxf(v3, 0.f);
                }
                const long base = ((long)bi * ldo + mg) * HW_N + nn;
                if (OUT_MODE == 1) {
                    union { bf16 h[4]; uint2 u2; } pk;
                    pk.h[0] = (bf16)v0; pk.h[1] = (bf16)v1;
                    pk.h[2] = (bf16)v2; pk.h[3] = (bf16)v3;
                    *(uint2*)&((bf16*)OUT)[base] = pk.u2;
                } else {
                    *(float4*)&((float*)OUT)[base] = make_float4(v0, v1, v2, v3);
                }
            }
        }
    }
}

// ---------------------------------------------------------------------------
// Sinkhorn passes (dust row analytic). Z[b][64][HW_N] f32.
// ---------------------------------------------------------------------------
template<bool FIRST>
__global__ __launch_bounds__(256)
void sink_u(const float* __restrict__ Z, const float* __restrict__ v,
            const float* __restrict__ alpha, float* __restrict__ u)
{
    const int b = blockIdx.y;
    const int i = blockIdx.x * 4 + (threadIdx.x >> 6);
    if (i > KK) return;
    const int lane = threadIdx.x & 63;
    const float* zr = Z + ((long)b * KK + i) * HW_N;
    const float* vb = v + (long)b * HW_N;
    const float a = alpha[0];
    float m = -INFINITY, s = 0.f;
    for (int j = lane; j < HW_N; j += 64) {
        float val = (i < KK) ? zr[j] : a;
        if (!FIRST) val += vb[j];
        float mn = fmaxf(m, val);
        s = s * __expf(m - mn) + __expf(val - mn);
        m = mn;
    }
    #pragma unroll
    for (int off = 32; off; off >>= 1) {
        float m2 = __shfl_xor(m, off), s2 = __shfl_xor(s, off);
        float mn = fmaxf(m, m2);
        s = s * __expf(m - mn) + s2 * __expf(m2 - mn);
        m = mn;
    }
    if (lane == 0) {
        const float norm = -logf(NORM_ARG);
        const float logmu = (i < KK) ? norm : (logf((float)(HW_N - KK)) + norm);
        u[b * M1 + i] = logmu - (m + __logf(s));
    }
}

__global__ __launch_bounds__(64)
void sink_v(const float* __restrict__ Z, const float* __restrict__ u,
            const float* __restrict__ alpha, float* __restrict__ v)
{
    const int b = blockIdx.y;
    const int n = blockIdx.x * 64 + threadIdx.x;
    const float* ub = u + b * M1;
    const float* Zb = Z + (long)b * KK * HW_N;
    float m = alpha[0] + ub[KK];
    float s = 1.f;
    for (int i = 0; i < KK; i++) {
        float t = Zb[(long)i * HW_N + n] + ub[i];
        float mn = fmaxf(m, t);
        s = s * __expf(m - mn) + __expf(t - mn);
        m = mn;
    }
    const float norm = -logf(NORM_ARG);
    v[(long)b * HW_N + n] = norm - (m + __logf(s));
}

// ---------------------------------------------------------------------------
// Pooling partials + finalize
// ---------------------------------------------------------------------------
__global__ __launch_bounds__(256)
void agg_partial(const bf16* __restrict__ f, const float* __restrict__ Z,
                 const float* __restrict__ u, const float* __restrict__ v,
                 float* __restrict__ part)
{
    const int c = blockIdx.x;
    const int b = blockIdx.y;
    const int n0 = c << 8;
    const float norm = -logf(NORM_ARG);

    __shared__ float Fs[16][132];
    __shared__ float Ps[16][68];

    const bf16*  fb = f + (long)b * DD * HW_N;
    const float* Zb = Z + (long)b * KK * HW_N;
    const float* ub = u + b * M1;
    const float* vb = v + (long)b * HW_N;

    const int tid = threadIdx.x;
    const int td = tid & 31;
    const int tk = tid >> 5;

    float acc[4][8] = {};

    for (int nt = 0; nt < 256; nt += 16) {
        #pragma unroll
        for (int i = 0; i < 8; i++) {
            int li = tid + (i << 8);
            int d = li >> 4, nn = li & 15;
            Fs[nn][d] = (float)fb[(long)d * HW_N + n0 + nt + nn];
        }
        #pragma unroll
        for (int i = 0; i < 4; i++) {
            int li = tid + (i << 8);
            int k = li >> 4, nn = li & 15;
            int n = n0 + nt + nn;
            Ps[nn][k] = __expf(Zb[(long)k * HW_N + n] + ub[k] + vb[n] - norm);
        }
        __syncthreads();
        #pragma unroll
        for (int nn = 0; nn < 16; nn++) {
            const float4 av = *reinterpret_cast<const float4*>(&Fs[nn][td << 2]);
            const float4 p0 = *reinterpret_cast<const float4*>(&Ps[nn][tk << 3]);
            const float4 p1 = *reinterpret_cast<const float4*>(&Ps[nn][(tk << 3) + 4]);
            float a[4] = {av.x, av.y, av.z, av.w};
            float p[8] = {p0.x, p0.y, p0.z, p0.w, p1.x, p1.y, p1.z, p1.w};
            #pragma unroll
            for (int i = 0; i < 4; i++)
                #pragma unroll
                for (int j = 0; j < 8; j++)
                    acc[i][j] += a[i] * p[j];
        }
        __syncthreads();
    }

    float* pb = part + (long)(b * 9 + c) * (DD * KK);
    #pragma unroll
    for (int i = 0; i < 4; i++) {
        int d = (td << 2) + i;
        float4 o0 = make_float4(acc[i][0], acc[i][1], acc[i][2], acc[i][3]);
        float4 o1 = make_float4(acc[i][4], acc[i][5], acc[i][6], acc[i][7]);
        *reinterpret_cast<float4*>(&pb[d * KK + (tk << 3)]) = o0;
        *reinterpret_cast<float4*>(&pb[d * KK + (tk << 3) + 4]) = o1;
    }
}

__global__ __launch_bounds__(256)
void finalize(const float* __restrict__ part, float* __restrict__ out)
{
    const int b = blockIdx.x;
    __shared__ float agg[DD * KK];
    __shared__ float nrm[KK];
    const int tid = threadIdx.x;

    for (int idx = tid; idx < DD * KK; idx += 256) {
        float s = 0.f;
        #pragma unroll
        for (int cc = 0; cc < 9; cc++)
            s += part[(long)(b * 9 + cc) * (DD * KK) + idx];
        agg[idx] = s;
    }
    __syncthreads();
    if (tid < KK) {
        float ss = 0.f;
        for (int d = 0; d < DD; d++) { float t = agg[d * KK + tid]; ss += t * t; }
        nrm[tid] = fmaxf(sqrtf(ss), 1e-12f);
    }
    __syncthreads();
    for (int idx = tid; idx < DD * KK; idx += 256)
        out[(long)b * (DD * KK) + idx] = agg[idx] / nrm[idx & 63];
}

// ---------------------------------------------------------------------------
extern "C" void kernel_launch(void* const* d_in, const int* in_sizes, int n_in,
                              void* d_out, int out_size, void* d_ws, size_t ws_size,
                              hipStream_t stream)
{
    const float* x     = (const float*)d_in[0];
    const float* w1    = (const float*)d_in[1];
    const float* b1    = (const float*)d_in[2];
    const float* w2    = (const float*)d_in[3];
    const float* b2    = (const float*)d_in[4];
    const float* s1    = (const float*)d_in[5];
    const float* c1    = (const float*)d_in[6];
    const float* s2    = (const float*)d_in[7];
    const float* c2    = (const float*)d_in[8];
    const float* alpha = (const float*)d_in[9];
    float* out = (float*)d_out;

    char* p = (char*)d_ws;
    bf16* Wc  = (bf16*)p;  p += (long)HID2 * CB * 2;
    bf16* w2b = (bf16*)p;  p += (long)DD * HIDD * 2;
    bf16* s2b = (bf16*)p;  p += (long)KK * HIDD * 2;
    float* bc = (float*)p; p += (long)HID2 * 4;
    bf16* xT  = (bf16*)p;  p += (long)NTOK * CB * 2;
    bf16* hs  = (bf16*)p;  p += (long)NTOK * HID2 * 2;
    bf16* f   = (bf16*)p;  p += (long)BATCH * DD * HW_N * 2;
    float* Z  = (float*)p; p += (long)BATCH * KK * HW_N * 4;
    float* u  = (float*)p; p += (long)BATCH * M1 * 4;
    float* v  = (float*)p; p += (long)BATCH * HW_N * 4;
    float* part = (float*)p;

    f2bf4<<<(HIDD * CB / 4 + 255) / 256, 256, 0, stream>>>(w1, Wc, HIDD * CB / 4);
    f2bf4<<<(HIDD * CB / 4 + 255) / 256, 256, 0, stream>>>(s1, Wc + (long)HIDD * CB, HIDD * CB / 4);
    f2bf4<<<(DD * HIDD / 4 + 255) / 256, 256, 0, stream>>>(w2, w2b, DD * HIDD / 4);
    f2bf4<<<(KK * HIDD / 4 + 255) / 256, 256, 0, stream>>>(s2, s2b, KK * HIDD / 4);
    concat_bias<<<4, 256, 0, stream>>>(b1, c1, bc);

    x_to_bf16T<<<dim3(36, 6, 32), 256, 0, stream>>>(x, xT);

    // stage 1 (fused w1||s1): hs[tok][1024] = relu(xT @ Wc^T + bc)
    // 256x256 tile, BK=32, 8 waves, counted vmcnt.  grid 4*288 = 1152 (%8==0)
    mfma_gemm8<8, 4, 32, 0, true, 2><<<1152, 512, 0, stream>>>(
        Wc, CB, xT, CB, bc, hs, HID2, CB, HID2 / 256);

    // stage 2a: f[b][d][n] = hs[:, 0:512] @ w2^T + b2   (128x128, BK=64)
    mfma_gemm8<4, 2, 64, 1, false, 4><<<NTOK / 128, 512, 0, stream>>>(
        hs, HID2, w2b, HIDD, b2, f, DD, HIDD, NTOK / 128);

    // stage 2b: Z[b][k][n] = hs[:, 512:1024] @ s2^T + c2  (128x64, BK=64)
    mfma_gemm8<4, 1, 64, 2, false, 4><<<NTOK / 128, 512, 0, stream>>>(
        hs + HIDD, HID2, s2b, HIDD, c2, Z, KK, HIDD, NTOK / 128);

    sink_u<true ><<<dim3(17, 32), 256, 0, stream>>>(Z, v, alpha, u);
    sink_v<<<dim3(36, 32), 64, 0, stream>>>(Z, u, alpha, v);
    sink_u<false><<<dim3(17, 32), 256, 0, stream>>>(Z, v, alpha, u);
    sink_v<<<dim3(36, 32), 64, 0, stream>>>(Z, u, alpha, v);
    sink_u<false><<<dim3(17, 32), 256, 0, stream>>>(Z, v, alpha, u);
    sink_v<<<dim3(36, 32), 64, 0, stream>>>(Z, u, alpha, v);

    agg_partial<<<dim3(9, 32), 256, 0, stream>>>(f, Z, u, v, part);
    finalize<<<32, 256, 0, stream>>>(part, out);
}

// Round 7
// 293.229 us; speedup vs baseline: 1.1141x; 1.1141x over previous
//
#include <hip/hip_runtime.h>
#include <math.h>
#include <stdint.h>

#define HW_N 2304
#define CB   384
#define HIDD 512
#define HID2 1024      // fused w1||s1
#define DD   128
#define KK   64
#define BATCH 32
#define M1   65
#define NTOK (BATCH * HW_N)   // 73728 flattened tokens
#define NORM_ARG 2368.0f

typedef __bf16 bf16;
typedef __bf16 bf16x8 __attribute__((ext_vector_type(8)));
typedef float  f32x4  __attribute__((ext_vector_type(4)));

__device__ __forceinline__ void gld16(void* lds, const void* g) {
    __builtin_amdgcn_global_load_lds(
        (const __attribute__((address_space(1))) uint32_t*)g,
        (__attribute__((address_space(3))) uint32_t*)lds, 16, 0, 0);
}

template<int N> __device__ __forceinline__ void waitvm() {
    if constexpr (N == 0) asm volatile("s_waitcnt vmcnt(0)" ::: "memory");
    else if constexpr (N == 1) asm volatile("s_waitcnt vmcnt(1)" ::: "memory");
    else if constexpr (N == 2) asm volatile("s_waitcnt vmcnt(2)" ::: "memory");
    else if constexpr (N == 3) asm volatile("s_waitcnt vmcnt(3)" ::: "memory");
    else if constexpr (N == 4) asm volatile("s_waitcnt vmcnt(4)" ::: "memory");
    else if constexpr (N == 5) asm volatile("s_waitcnt vmcnt(5)" ::: "memory");
    else if constexpr (N == 6) asm volatile("s_waitcnt vmcnt(6)" ::: "memory");
    else asm volatile("s_waitcnt vmcnt(8)" ::: "memory");
}

// ---------------------------------------------------------------------------
// x[b][CB][HW_N] f32 -> xT[b][HW_N][CB] bf16, all batches
// ---------------------------------------------------------------------------
__global__ __launch_bounds__(256)
void x_to_bf16T(const float* __restrict__ x, bf16* __restrict__ xT)
{
    const int b  = blockIdx.z;
    const int n0 = blockIdx.x * 64;
    const int c0 = blockIdx.y * 64;
    __shared__ float t[64][65];
    const int tx = threadIdx.x & 15, ty = threadIdx.x >> 4;
    const float* xb = x + (long)b * CB * HW_N;
    #pragma unroll
    for (int r = 0; r < 64; r += 16) {
        const float4 vv = *(const float4*)&xb[(long)(c0 + r + ty) * HW_N + n0 + tx * 4];
        t[r + ty][tx * 4 + 0] = vv.x; t[r + ty][tx * 4 + 1] = vv.y;
        t[r + ty][tx * 4 + 2] = vv.z; t[r + ty][tx * 4 + 3] = vv.w;
    }
    __syncthreads();
    bf16* ob = xT + (long)b * HW_N * CB;
    #pragma unroll
    for (int r = 0; r < 64; r += 16) {
        const int n = r + ty;
        union { bf16 h[4]; uint2 u2; } pk;
        pk.h[0] = (bf16)t[tx * 4 + 0][n]; pk.h[1] = (bf16)t[tx * 4 + 1][n];
        pk.h[2] = (bf16)t[tx * 4 + 2][n]; pk.h[3] = (bf16)t[tx * 4 + 3][n];
        *(uint2*)&ob[(long)(n0 + n) * CB + c0 + tx * 4] = pk.u2;
    }
}

// ---------------------------------------------------------------------------
// One-shot weight/bias prep: Wc = bf16(w1||s1) [1024][384],
// Wf = bf16(w2||s2) [192][512], bc = f32(b1||c1) [1024].
// ---------------------------------------------------------------------------
__device__ __forceinline__ void cvtq(const float* __restrict__ in,
                                     bf16* __restrict__ out, int q)
{
    float4 vv = ((const float4*)in)[q];
    union { bf16 h[4]; uint2 u2; } pk;
    pk.h[0] = (bf16)vv.x; pk.h[1] = (bf16)vv.y;
    pk.h[2] = (bf16)vv.z; pk.h[3] = (bf16)vv.w;
    ((uint2*)out)[q] = pk.u2;
}

__global__ __launch_bounds__(256)
void prep_weights(const float* __restrict__ w1, const float* __restrict__ s1,
                  const float* __restrict__ w2, const float* __restrict__ s2,
                  const float* __restrict__ b1, const float* __restrict__ c1,
                  bf16* __restrict__ Wc, bf16* __restrict__ Wf,
                  float* __restrict__ bc)
{
    const int QW1 = HIDD * CB / 4;    // 49152
    const int QW2 = DD * HIDD / 4;    // 16384
    const int QS2 = KK * HIDD / 4;    // 8192
    int i = blockIdx.x * 256 + threadIdx.x;
    if (i < QW1)                       { cvtq(w1, Wc, i); return; }
    i -= QW1;
    if (i < QW1)                       { cvtq(s1, Wc + (long)HIDD * CB, i); return; }
    i -= QW1;
    if (i < QW2)                       { cvtq(w2, Wf, i); return; }
    i -= QW2;
    if (i < QS2)                       { cvtq(s2, Wf + (long)DD * HIDD, i); return; }
    i -= QS2;
    if (i < 256) {                     // bc: 1024 f32 = 256 float4
        float4 vv = (i < 128) ? ((const float4*)b1)[i] : ((const float4*)c1)[i - 128];
        ((float4*)bc)[i] = vv;
    }
}

// ---------------------------------------------------------------------------
// 4-wave counted-vmcnt MFMA GEMM (256 threads, waves 2x2), BK=32.
//   OUT(ra, rb) = act( A[ra][:K] . B[rb][:K] + bias )
// r5 geometry (128-class tiles, 32KB LDS dbuf, 5 blocks/CU) with ONLY the
// sync structure changed (this round's single variable):
//   loop: ds_read cur; MFMA; lgkmcnt(0); s_barrier;     // release cur
//         stage(cur <- t+2); vmcnt(GAB) [never 0 mid-loop]; s_barrier;
// The counted wait releases the barrier as soon as tile t+1 landed while
// tile t+2's GAB loads stay in flight across it (T4, m218).
// SQ_LDS_BANK_CONFLICT == 8 per gld16 is the DMA's own LDS-write burst
// (measured invariant r3-r6) — ignore it.
// OUT_MODE 0: OUT[rb][ra] bf16 (bias on ra, packed along ra)
// OUT_MODE 1: ra = token -> (b, n); OUT[((b*ldo)+rb)*HW_N + n] bf16
// OUT_MODE 2: same addressing, f32 (bias on rb for modes 1/2)
// ---------------------------------------------------------------------------
template<int FA, int FB, int OUT_MODE, bool RELU, int MINW>
__global__ __launch_bounds__(256, MINW)
void mfma_gemm4(const bf16* __restrict__ A, int lda,
                const bf16* __restrict__ B, int ldb,
                const float* __restrict__ bias,
                void* __restrict__ OUT, int ldo,
                int K, int nA)
{
    constexpr int BA = 2 * FA * 16;
    constexpr int BB = 2 * FB * 16;
    constexpr int ROWB = 64;                 // BK=32 -> 64 B rows
    constexpr int GA = (BA * ROWB) / 4096;   // gld16 per wave, A tile
    constexpr int GB = (BB * ROWB) / 4096;
    constexpr int GAB = GA + GB;

    __shared__ __align__(16) bf16 As[2][BA * 32];
    __shared__ __align__(16) bf16 Bs[2][BB * 32];

    int L = blockIdx.x;
    { const int cpx = gridDim.x >> 3; L = (L & 7) * cpx + (L >> 3); }
    const int ta = L % nA;
    const int tb = L / nA;

    const int tid  = threadIdx.x;
    const int lane = tid & 63;
    const int w    = tid >> 6;           // 0..3
    const int wr   = w >> 1, wc = w & 1;

    const char* Ap = (const char*)A + (long)ta * BA * lda * 2;
    const char* Bp = (const char*)B + (long)tb * BB * ldb * 2;
    const long ldab = (long)lda * 2, ldbb = (long)ldb * 2;

    // staging lane constants: wave chunk = 1 KiB = 16 rows x 64 B
    const int subrow = lane >> 2;        // 0..15
    const int colb   = (lane & 3) << 4;  // 16B slot in row

    // frag-read lane constants
    const int rl = lane & 15, q = lane >> 4;

    f32x4 acc[FA][FB];
    #pragma unroll
    for (int i = 0; i < FA; i++)
        #pragma unroll
        for (int j = 0; j < FB; j++)
            acc[i][j] = (f32x4){0.f, 0.f, 0.f, 0.f};

    const int nsteps = K / 32;

    auto stageA = [&](int buf, int kt) {
        #pragma unroll
        for (int g = 0; g < GA; ++g) {
            const int ii = g * 4 + w;
            gld16((char*)As[buf] + ii * 1024,
                  Ap + (long)(ii * 16 + subrow) * ldab + (long)kt * ROWB + colb);
        }
    };
    auto stageB = [&](int buf, int kt) {
        #pragma unroll
        for (int g = 0; g < GB; ++g) {
            const int ii = g * 4 + w;
            gld16((char*)Bs[buf] + ii * 1024,
                  Bp + (long)(ii * 16 + subrow) * ldbb + (long)kt * ROWB + colb);
        }
    };

    // prologue: two tiles in flight, wait only for tile 0
    stageA(0, 0); stageB(0, 0);
    stageA(1, 1); stageB(1, 1);
    waitvm<GAB>();
    __builtin_amdgcn_s_barrier();

    for (int t = 0; t < nsteps; ++t) {
        const int cur = t & 1;
        const char* Ab = (const char*)As[cur];
        const char* Bb = (const char*)Bs[cur];

        bf16x8 a[FA], bb[FB];
        #pragma unroll
        for (int i = 0; i < FA; i++)
            a[i] = *(const bf16x8*)(Ab + (wr * FA * 16 + i * 16 + rl) * ROWB + (q << 4));
        #pragma unroll
        for (int j = 0; j < FB; j++)
            bb[j] = *(const bf16x8*)(Bb + (wc * FB * 16 + j * 16 + rl) * ROWB + (q << 4));

        __builtin_amdgcn_s_setprio(1);
        #pragma unroll
        for (int i = 0; i < FA; i++)
            #pragma unroll
            for (int j = 0; j < FB; j++)
                acc[i][j] = __builtin_amdgcn_mfma_f32_16x16x32_bf16(a[i], bb[j], acc[i][j], 0, 0, 0);
        __builtin_amdgcn_s_setprio(0);

        asm volatile("s_waitcnt lgkmcnt(0)" ::: "memory");  // my reads of cur done
        __builtin_amdgcn_s_barrier();                       // all reads of cur done
        if (t + 2 < nsteps) { stageA(cur, t + 2); stageB(cur, t + 2); }
        if (t + 1 < nsteps) {
            if (t + 2 < nsteps) waitvm<GAB>(); else waitvm<0>();
            __builtin_amdgcn_s_barrier();                   // next buffer ready
        }
    }

    const int fr = lane & 15;
    const int fq = lane >> 4;

    if (OUT_MODE == 0) {
        #pragma unroll
        for (int i = 0; i < FA; i++) {
            const int ra0 = ta * BA + wr * FA * 16 + i * 16 + fq * 4;
            const float4 bv = *(const float4*)&bias[ra0];
            #pragma unroll
            for (int j = 0; j < FB; j++) {
                const int rb = tb * BB + wc * FB * 16 + j * 16 + fr;
                union { bf16 h[4]; uint2 u2; } pk;
                float v0 = acc[i][j][0] + bv.x, v1 = acc[i][j][1] + bv.y;
                float v2 = acc[i][j][2] + bv.z, v3 = acc[i][j][3] + bv.w;
                if (RELU) {
                    v0 = fmaxf(v0, 0.f); v1 = fmaxf(v1, 0.f);
                    v2 = fmaxf(v2, 0.f); v3 = fmaxf(v3, 0.f);
                }
                pk.h[0] = (bf16)v0; pk.h[1] = (bf16)v1;
                pk.h[2] = (bf16)v2; pk.h[3] = (bf16)v3;
                *(uint2*)&((bf16*)OUT)[(long)rb * ldo + ra0] = pk.u2;
            }
        }
    } else {
        #pragma unroll
        for (int i = 0; i < FA; i++) {
            const int g0 = ta * BA + wr * FA * 16 + i * 16 + fq * 4;
            const int bi = g0 / HW_N;
            const int nn = g0 - bi * HW_N;
            #pragma unroll
            for (int j = 0; j < FB; j++) {
                const int mg = tb * BB + wc * FB * 16 + j * 16 + fr;
                const float bvs = bias[mg];
                float v0 = acc[i][j][0] + bvs, v1 = acc[i][j][1] + bvs;
                float v2 = acc[i][j][2] + bvs, v3 = acc[i][j][3] + bvs;
                if (RELU) {
                    v0 = fmaxf(v0, 0.f); v1 = fmaxf(v1, 0.f);
                    v2 = fmaxf(v2, 0.f); v3 = fmaxf(v3, 0.f);
                }
                const long base = ((long)bi * ldo + mg) * HW_N + nn;
                if (OUT_MODE == 1) {
                    union { bf16 h[4]; uint2 u2; } pk;
                    pk.h[0] = (bf16)v0; pk.h[1] = (bf16)v1;
                    pk.h[2] = (bf16)v2; pk.h[3] = (bf16)v3;
                    *(uint2*)&((bf16*)OUT)[base] = pk.u2;
                } else {
                    *(float4*)&((float*)OUT)[base] = make_float4(v0, v1, v2, v3);
                }
            }
        }
    }
}

// ---------------------------------------------------------------------------
// Sinkhorn passes (dust row analytic). Z[b][64][HW_N] f32.
// ---------------------------------------------------------------------------
template<bool FIRST>
__global__ __launch_bounds__(256)
void sink_u(const float* __restrict__ Z, const float* __restrict__ v,
            const float* __restrict__ alpha, float* __restrict__ u)
{
    const int b = blockIdx.y;
    const int i = blockIdx.x * 4 + (threadIdx.x >> 6);
    if (i > KK) return;
    const int lane = threadIdx.x & 63;
    const float* zr = Z + ((long)b * KK + i) * HW_N;
    const float* vb = v + (long)b * HW_N;
    const float a = alpha[0];
    float m = -INFINITY, s = 0.f;
    for (int j = lane; j < HW_N; j += 64) {
        float val = (i < KK) ? zr[j] : a;
        if (!FIRST) val += vb[j];
        float mn = fmaxf(m, val);
        s = s * __expf(m - mn) + __expf(val - mn);
        m = mn;
    }
    #pragma unroll
    for (int off = 32; off; off >>= 1) {
        float m2 = __shfl_xor(m, off), s2 = __shfl_xor(s, off);
        float mn = fmaxf(m, m2);
        s = s * __expf(m - mn) + s2 * __expf(m2 - mn);
        m = mn;
    }
    if (lane == 0) {
        const float norm = -logf(NORM_ARG);
        const float logmu = (i < KK) ? norm : (logf((float)(HW_N - KK)) + norm);
        u[b * M1 + i] = logmu - (m + __logf(s));
    }
}

__global__ __launch_bounds__(64)
void sink_v(const float* __restrict__ Z, const float* __restrict__ u,
            const float* __restrict__ alpha, float* __restrict__ v)
{
    const int b = blockIdx.y;
    const int n = blockIdx.x * 64 + threadIdx.x;
    const float* ub = u + b * M1;
    const float* Zb = Z + (long)b * KK * HW_N;
    float m = alpha[0] + ub[KK];
    float s = 1.f;
    for (int i = 0; i < KK; i++) {
        float t = Zb[(long)i * HW_N + n] + ub[i];
        float mn = fmaxf(m, t);
        s = s * __expf(m - mn) + __expf(t - mn);
        m = mn;
    }
    const float norm = -logf(NORM_ARG);
    v[(long)b * HW_N + n] = norm - (m + __logf(s));
}

// ---------------------------------------------------------------------------
// Pooling partials + finalize
// ---------------------------------------------------------------------------
__global__ __launch_bounds__(256)
void agg_partial(const bf16* __restrict__ f, const float* __restrict__ Z,
                 const float* __restrict__ u, const float* __restrict__ v,
                 float* __restrict__ part)
{
    const int c = blockIdx.x;
    const int b = blockIdx.y;
    const int n0 = c << 8;
    const float norm = -logf(NORM_ARG);

    __shared__ float Fs[16][132];
    __shared__ float Ps[16][68];

    const bf16*  fb = f + (long)b * DD * HW_N;
    const float* Zb = Z + (long)b * KK * HW_N;
    const float* ub = u + b * M1;
    const float* vb = v + (long)b * HW_N;

    const int tid = threadIdx.x;
    const int td = tid & 31;
    const int tk = tid >> 5;

    float acc[4][8] = {};

    for (int nt = 0; nt < 256; nt += 16) {
        #pragma unroll
        for (int i = 0; i < 8; i++) {
            int li = tid + (i << 8);
            int d = li >> 4, nn = li & 15;
            Fs[nn][d] = (float)fb[(long)d * HW_N + n0 + nt + nn];
        }
        #pragma unroll
        for (int i = 0; i < 4; i++) {
            int li = tid + (i << 8);
            int k = li >> 4, nn = li & 15;
            int n = n0 + nt + nn;
            Ps[nn][k] = __expf(Zb[(long)k * HW_N + n] + ub[k] + vb[n] - norm);
        }
        __syncthreads();
        #pragma unroll
        for (int nn = 0; nn < 16; nn++) {
            const float4 av = *reinterpret_cast<const float4*>(&Fs[nn][td << 2]);
            const float4 p0 = *reinterpret_cast<const float4*>(&Ps[nn][tk << 3]);
            const float4 p1 = *reinterpret_cast<const float4*>(&Ps[nn][(tk << 3) + 4]);
            float a[4] = {av.x, av.y, av.z, av.w};
            float p[8] = {p0.x, p0.y, p0.z, p0.w, p1.x, p1.y, p1.z, p1.w};
            #pragma unroll
            for (int i = 0; i < 4; i++)
                #pragma unroll
                for (int j = 0; j < 8; j++)
                    acc[i][j] += a[i] * p[j];
        }
        __syncthreads();
    }

    float* pb = part + (long)(b * 9 + c) * (DD * KK);
    #pragma unroll
    for (int i = 0; i < 4; i++) {
        int d = (td << 2) + i;
        float4 o0 = make_float4(acc[i][0], acc[i][1], acc[i][2], acc[i][3]);
        float4 o1 = make_float4(acc[i][4], acc[i][5], acc[i][6], acc[i][7]);
        *reinterpret_cast<float4*>(&pb[d * KK + (tk << 3)]) = o0;
        *reinterpret_cast<float4*>(&pb[d * KK + (tk << 3) + 4]) = o1;
    }
}

__global__ __launch_bounds__(256)
void finalize(const float* __restrict__ part, float* __restrict__ out)
{
    const int b = blockIdx.x;
    __shared__ float agg[DD * KK];
    __shared__ float nrm[KK];
    const int tid = threadIdx.x;

    for (int idx = tid; idx < DD * KK; idx += 256) {
        float s = 0.f;
        #pragma unroll
        for (int cc = 0; cc < 9; cc++)
            s += part[(long)(b * 9 + cc) * (DD * KK) + idx];
        agg[idx] = s;
    }
    __syncthreads();
    if (tid < KK) {
        float ss = 0.f;
        for (int d = 0; d < DD; d++) { float t = agg[d * KK + tid]; ss += t * t; }
        nrm[tid] = fmaxf(sqrtf(ss), 1e-12f);
    }
    __syncthreads();
    for (int idx = tid; idx < DD * KK; idx += 256)
        out[(long)b * (DD * KK) + idx] = agg[idx] / nrm[idx & 63];
}

// ---------------------------------------------------------------------------
extern "C" void kernel_launch(void* const* d_in, const int* in_sizes, int n_in,
                              void* d_out, int out_size, void* d_ws, size_t ws_size,
                              hipStream_t stream)
{
    const float* x     = (const float*)d_in[0];
    const float* w1    = (const float*)d_in[1];
    const float* b1    = (const float*)d_in[2];
    const float* w2    = (const float*)d_in[3];
    const float* b2    = (const float*)d_in[4];
    const float* s1    = (const float*)d_in[5];
    const float* c1    = (const float*)d_in[6];
    const float* s2    = (const float*)d_in[7];
    const float* c2    = (const float*)d_in[8];
    const float* alpha = (const float*)d_in[9];
    float* out = (float*)d_out;

    char* p = (char*)d_ws;
    bf16* Wc  = (bf16*)p;  p += (long)HID2 * CB * 2;        // w1||s1
    bf16* Wf  = (bf16*)p;  p += (long)(DD + KK) * HIDD * 2; // w2||s2
    float* bc = (float*)p; p += (long)HID2 * 4;             // b1||c1
    bf16* xT  = (bf16*)p;  p += (long)NTOK * CB * 2;
    bf16* hs  = (bf16*)p;  p += (long)NTOK * HID2 * 2;
    bf16* f   = (bf16*)p;  p += (long)BATCH * DD * HW_N * 2;
    float* Z  = (float*)p; p += (long)BATCH * KK * HW_N * 4;
    float* u  = (float*)p; p += (long)BATCH * M1 * 4;
    float* v  = (float*)p; p += (long)BATCH * HW_N * 4;
    float* part = (float*)p;

    prep_weights<<<481, 256, 0, stream>>>(w1, s1, w2, s2, b1, c1, Wc, Wf, bc);

    x_to_bf16T<<<dim3(36, 6, 32), 256, 0, stream>>>(x, xT);

    // stage 1 (fused w1||s1): hs[tok][1024] = relu(xT @ Wc^T + bc)
    // 128x128 tile, BK=32, 4 waves, counted vmcnt; grid 8*576 = 4608 (%8==0)
    mfma_gemm4<4, 4, 0, true, 4><<<4608, 256, 0, stream>>>(
        Wc, CB, xT, CB, bc, hs, HID2, CB, HID2 / 128);

    // stage 2a: f[b][d][n] = hs[:, 0:512] @ w2^T + b2   (128x128, BK=32)
    mfma_gemm4<4, 4, 1, false, 4><<<NTOK / 128, 256, 0, stream>>>(
        hs, HID2, Wf, HIDD, b2, f, DD, HIDD, NTOK / 128);

    // stage 2b: Z[b][k][n] = hs[:, 512:1024] @ s2^T + c2  (128x64, BK=32)
    mfma_gemm4<4, 2, 2, false, 4><<<NTOK / 128, 256, 0, stream>>>(
        hs + HIDD, HID2, Wf + (long)DD * HIDD, HIDD, c2, Z, KK, HIDD, NTOK / 128);

    sink_u<true ><<<dim3(17, 32), 256, 0, stream>>>(Z, v, alpha, u);
    sink_v<<<dim3(36, 32), 64, 0, stream>>>(Z, u, alpha, v);
    sink_u<false><<<dim3(17, 32), 256, 0, stream>>>(Z, v, alpha, u);
    sink_v<<<dim3(36, 32), 64, 0, stream>>>(Z, u, alpha, v);
    sink_u<false><<<dim3(17, 32), 256, 0, stream>>>(Z, v, alpha, u);
    sink_v<<<dim3(36, 32), 64, 0, stream>>>(Z, u, alpha, v);

    agg_partial<<<dim3(9, 32), 256, 0, stream>>>(f, Z, u, v, part);
    finalize<<<32, 256, 0, stream>>>(part, out);
}